// Round 10
// baseline (360.055 us; speedup 1.0000x reference)
//
#include <hip/hip_runtime.h>
#include <hip/hip_bf16.h>
#include <stdint.h>

#define S_LEN 2048
#define HD 128
#define QBLK 128
#define KVBLK 64
#define TPB 512
#define NBH 32
#define NKT (S_LEN / KVBLK)      // 32 kv tiles
#define KIMG_TILE 16384          // 64x128 f16 LDS image bytes

typedef __attribute__((ext_vector_type(8))) _Float16 f16x8;
typedef __attribute__((ext_vector_type(8))) short s16x8;
typedef __attribute__((ext_vector_type(4))) float f32x4;

__device__ __forceinline__ short f2h(float f) {
  _Float16 h = (_Float16)f;
  return __builtin_bit_cast(short, h);
}
__device__ __forceinline__ unsigned short f2b(float f) {
  union { float fv; unsigned u; } v; v.fv = f;
  unsigned r = v.u + 0x7fffu + ((v.u >> 16) & 1u);
  return (unsigned short)(r >> 16);
}
__device__ __forceinline__ float b2f(unsigned short h) {
  union { unsigned u; float fv; } v; v.u = ((unsigned)h) << 16; return v.fv;
}
__device__ __forceinline__ unsigned pkrtz(float a, float b) {
  return __builtin_bit_cast(unsigned, __builtin_amdgcn_cvt_pkrtz(a, b));
}

typedef __attribute__((address_space(3))) uint32_t lds_u32_t;
typedef __attribute__((address_space(1))) const uint32_t glb_u32_t;
__device__ __forceinline__ void gll16(const void* g, void* l) {
  __builtin_amdgcn_global_load_lds((glb_u32_t*)g, (lds_u32_t*)l, 16, 0, 0);
}

// ============================================================================
// Pre-pass (unchanged from R8): K -> f16 swizzled image; V -> Vt[d][kv] image.
// ============================================================================
__global__ __launch_bounds__(256) void prep_kv(
    const float* __restrict__ Kg, const float* __restrict__ Vg,
    char* __restrict__ KfI, char* __restrict__ VtI) {
  __shared__ __align__(16) char vlds[64 * 528];
  const int t = threadIdx.x;
  const int bh = blockIdx.x >> 5;
  const int kt = blockIdx.x & 31;
  const size_t base = ((size_t)bh * S_LEN + (size_t)kt * KVBLK) * HD;
  const size_t tbase = ((size_t)bh * NKT + kt) * KIMG_TILE;

  {
    const int row = t >> 2;
    const int c4 = (t & 3) * 32;
    const float* src = Kg + base + (size_t)row * HD + c4;
#pragma unroll
    for (int j8 = 0; j8 < 4; ++j8) {
      float4 a = *(const float4*)(src + j8 * 8);
      float4 b = *(const float4*)(src + j8 * 8 + 4);
      float vs[8] = {a.x, a.y, a.z, a.w, b.x, b.y, b.z, b.w};
      s16x8 h;
#pragma unroll
      for (int j = 0; j < 8; ++j) h[j] = f2h(vs[j]);
      int off = (row * 256 + (c4 + j8 * 8) * 2) ^ ((row & 7) << 4);
      *(s16x8*)(KfI + tbase + off) = h;
    }
  }

#pragma unroll
  for (int it = 0; it < 8; ++it) {
    int idx = it * 256 + t;
    int row = idx >> 5;
    int cb = (idx & 31) * 16;
    float4 v = *(const float4*)((const char*)(Vg + base + (size_t)row * HD) + cb);
    *(float4*)(vlds + row * 528 + cb) = v;
  }
  __syncthreads();
  {
    const int d = t & 127;
    const int kvb = (t >> 7) * 32;
#pragma unroll
    for (int jj = 0; jj < 4; ++jj) {
      s16x8 o;
#pragma unroll
      for (int j = 0; j < 8; ++j) {
        int kv = kvb + jj * 8 + j;
        float f = *(const float*)(vlds + kv * 528 + d * 4);
        o[j] = f2h(f);
      }
      int off = (d * 128 + (kvb + jj * 8) * 2) ^ ((d & 7) << 4);
      *(s16x8*)(VtI + tbase + off) = o;
    }
  }
}

// ============================================================================
// Swapped-operand attention: in-register softmax + register P (no Psm).
// LDS: Kf 16K | Vt 16K = 32KB single buffer.
// Lane (lm,lg) owns q-row qrow0+lm: scores kv=st*16+4*lg+r; acc O[q][d-subtile].
// ============================================================================
#define SMEMF5 32768

__global__ __launch_bounds__(TPB, 2) void attn_fwd5(
    const char* __restrict__ KfI, const char* __restrict__ VtI,
    const float* __restrict__ Qg, const int* __restrict__ Mg,
    float* __restrict__ Og) {
  __shared__ __align__(16) char smem[SMEMF5];

  const int tid = threadIdx.x;
  const int wave = tid >> 6;
  const int lane = tid & 63;
  const int lm = lane & 15;
  const int lg = lane >> 4;

  const int bh = blockIdx.x;
  const int q0 = blockIdx.y * QBLK;
  const int qrow0 = q0 + wave * 16;
  const size_t base = (size_t)bh * S_LEN * HD;
  const float* Qb = Qg + base;

  // ---- Q fragments: f16, 1/T = 1.25 folded. Layout: row=qrow0+lm, k=lg*8+e ----
  f16x8 qf[4];
#pragma unroll
  for (int c = 0; c < 4; ++c) {
    const float* src = Qb + (size_t)(qrow0 + lm) * HD + c * 32 + lg * 8;
    float4 a = *(const float4*)src;
    float4 b = *(const float4*)(src + 4);
    float qs[8] = {a.x, a.y, a.z, a.w, b.x, b.y, b.z, b.w};
    f16x8 f;
#pragma unroll
    for (int j = 0; j < 8; ++j) f[j] = (_Float16)(qs[j] * 1.25f);
    qf[c] = f;
  }

  // acc[dt][r] = O[qrow0+lm][dt*16 + 4*lg + r]  (O^T C/D: col=q=lm, row=d)
  f32x4 acc[8];
#pragma unroll
  for (int i = 0; i < 8; ++i) acc[i] = (f32x4){0.f, 0.f, 0.f, 0.f};
  float mrun = -1e30f;   // per-lane: running max of row qrow0+lm
  float lrun = 0.f;      // per-lane: running denom

  const int wo = wave * 2048 + lane * 16;
  const int* Mrow = Mg + (size_t)(qrow0 + lm) * S_LEN + 4 * lg;

  for (int kt = 0; kt < NKT; ++kt) {
    const int kv0 = kt * KVBLK;

    __syncthreads();  // all waves done reading buffer (previous tile)

    // ---- stage K,Vt tile via async global->LDS ----
    {
      const size_t tb = ((size_t)bh * NKT + kt) * KIMG_TILE;
      gll16(KfI + tb + wo,        smem + wave * 2048);
      gll16(KfI + tb + wo + 1024, smem + wave * 2048 + 1024);
      gll16(VtI + tb + wo,        smem + 16384 + wave * 2048);
      gll16(VtI + tb + wo + 1024, smem + 16384 + wave * 2048 + 1024);
    }
    // ---- mask: int4 per subtile, kv = kv0 + st*16 + 4*lg + r ----
    int4 mk4[4];
#pragma unroll
    for (int st = 0; st < 4; ++st)
      mk4[st] = *(const int4*)(Mrow + kv0 + st * 16);

    __syncthreads();  // stage + mask drained (vmcnt0 at barrier)

    // ---- QK^T swapped: S^T = mfma(K, Q^T); lane gets row q=lm, kv=st*16+4lg+r
    __builtin_amdgcn_s_setprio(1);
    f32x4 sf[4];
#pragma unroll
    for (int st = 0; st < 4; ++st) {
      f32x4 c = (f32x4){0.f, 0.f, 0.f, 0.f};
#pragma unroll
      for (int ch = 0; ch < 4; ++ch) {
        int krow = st * 16 + lm;
        int byo = (krow * 256 + ch * 64 + lg * 16) ^ ((krow & 7) << 4);
        f16x8 kf = *(const f16x8*)(smem + byo);
        c = __builtin_amdgcn_mfma_f32_16x16x32_f16(kf, qf[ch], c, 0, 0, 0);
      }
      sf[st] = c;
    }
    __builtin_amdgcn_s_setprio(0);

    // ---- mask + in-register online softmax (row fully lane-local + 2 shfl) ----
    float p[4][4];   // [st][r] scores then exp values
    float mx = -1e30f;
#pragma unroll
    for (int st = 0; st < 4; ++st) {
      int mr[4] = {mk4[st].x, mk4[st].y, mk4[st].z, mk4[st].w};
#pragma unroll
      for (int r = 0; r < 4; ++r) {
        float s = mr[r] ? sf[st][r] : -1e-9f;
        p[st][r] = s;
        mx = fmaxf(mx, s);
      }
    }
    mx = fmaxf(mx, __shfl_xor(mx, 16));
    mx = fmaxf(mx, __shfl_xor(mx, 32));

    bool need = mx > mrun + 8.f;       // defer-rescale (T13)
    if (__any(need)) {
      float mnew = fmaxf(mrun, mx);
      float scale = __expf(mrun - mnew);
      lrun *= scale;
      mrun = mnew;
#pragma unroll
      for (int dt = 0; dt < 8; ++dt) acc[dt] *= scale;
    }
    float ps = 0.f;
#pragma unroll
    for (int st = 0; st < 4; ++st)
#pragma unroll
      for (int r = 0; r < 4; ++r) {
        float e = __expf(p[st][r] - mrun);   // bounded by e^8
        p[st][r] = e;
        ps += e;
      }
    ps += __shfl_xor(ps, 16);
    ps += __shfl_xor(ps, 32);
    lrun += ps;

    // ---- pack P to f16 pairs: w[st][rp] = (p[st][2rp], p[st][2rp+1]) ----
    unsigned w[4][2];
#pragma unroll
    for (int st = 0; st < 4; ++st)
#pragma unroll
      for (int rp = 0; rp < 2; ++rp)
        w[st][rp] = pkrtz(p[st][2 * rp], p[st][2 * rp + 1]);

    // ---- PV swapped: O^T += V^T * P^T. B-frag built by lane redistribution:
    // word i of chunk kk = w[2kk+(lg>>1)][i&1] from lane lm+16*(2*(lg&1)+(i>>1))
#pragma unroll
    for (int kk = 0; kk < 2; ++kk) {
      int words[4];
#pragma unroll
      for (int i = 0; i < 4; ++i) {
        int src = lm + 16 * ((lg & 1) * 2 + (i >> 1));
        int wa = __shfl((int)w[2 * kk + 0][i & 1], src);
        int wb = __shfl((int)w[2 * kk + 1][i & 1], src);
        words[i] = (lg >> 1) ? wb : wa;
      }
      union { int v[4]; f16x8 h; } pb;
      pb.v[0] = words[0]; pb.v[1] = words[1];
      pb.v[2] = words[2]; pb.v[3] = words[3];

      __builtin_amdgcn_s_setprio(1);
#pragma unroll
      for (int dt = 0; dt < 8; ++dt) {
        int vrow = dt * 16 + lm;
        int byo = (vrow * 128 + (kk * 32 + lg * 8) * 2) ^ ((vrow & 7) << 4);
        f16x8 va = *(const f16x8*)(smem + 16384 + byo);
        acc[dt] = __builtin_amdgcn_mfma_f32_16x16x32_f16(va, pb.h, acc[dt], 0, 0, 0);
      }
      __builtin_amdgcn_s_setprio(0);
    }
  }

  // ---- epilogue: O[qrow0+lm][dt*16+4lg .. +3] = acc[dt] / lrun ----
  float invl = 1.f / lrun;
  float* ob = Og + base + (size_t)(qrow0 + lm) * HD;
#pragma unroll
  for (int dt = 0; dt < 8; ++dt) {
    float4 o;
    o.x = acc[dt][0] * invl;
    o.y = acc[dt][1] * invl;
    o.z = acc[dt][2] * invl;
    o.w = acc[dt][3] * invl;
    *(float4*)(ob + dt * 16 + 4 * lg) = o;
  }
}

// ============================================================================
// Fallback (Round-3 verified bf16 hi/lo kernel) if ws too small for images.
// ============================================================================
typedef __attribute__((ext_vector_type(8))) short bf16x8;
#define KSM_BYTES (KVBLK * HD * 2)
#define VSM_BYTES (HD * 72 * 2)
#define PSM_PER_WAVE (16 * 72 * 2)
#define SMEM_BYTES (2 * KSM_BYTES + VSM_BYTES + 8 * PSM_PER_WAVE)

__global__ __launch_bounds__(TPB, 2) void attn_fwd(
    const float* __restrict__ Kg, const float* __restrict__ Vg,
    const float* __restrict__ Qg, const int* __restrict__ Mg,
    float* __restrict__ Og) {
  __shared__ __align__(16) char smem[SMEM_BYTES];
  char* KsmH = smem;
  char* KsmL = smem + KSM_BYTES;
  char* Vsm = smem + 2 * KSM_BYTES;
  char* Psm = smem + 2 * KSM_BYTES + VSM_BYTES;

  const int tid = threadIdx.x;
  const int wave = tid >> 6;
  const int lane = tid & 63;
  const int lm = lane & 15;
  const int lg = lane >> 4;

  const int bh = blockIdx.x;
  const int q0 = blockIdx.y * QBLK;
  const int qrow0 = q0 + wave * 16;

  const size_t base = (size_t)bh * S_LEN * HD;
  const float* Kb = Kg + base;
  const float* Vb = Vg + base;
  const float* Qb = Qg + base;

  bf16x8 qhi[4], qlo[4];
#pragma unroll
  for (int c = 0; c < 4; ++c) {
    const float* src = Qb + (size_t)(qrow0 + lm) * HD + c * 32 + lg * 8;
    float4 a = *(const float4*)src;
    float4 b = *(const float4*)(src + 4);
    float qs[8] = {a.x, a.y, a.z, a.w, b.x, b.y, b.z, b.w};
    bf16x8 fh, fl;
#pragma unroll
    for (int j = 0; j < 8; ++j) {
      float v = qs[j] * 1.25f;
      unsigned short h = f2b(v);
      fh[j] = (short)h;
      fl[j] = (short)f2b(v - b2f(h));
    }
    qhi[c] = fh;
    qlo[c] = fl;
  }

  f32x4 acc[8];
#pragma unroll
  for (int i = 0; i < 8; ++i) acc[i] = (f32x4){0.f, 0.f, 0.f, 0.f};
  float mrun[4] = {-1e30f, -1e30f, -1e30f, -1e30f};
  float lrun[4] = {0.f, 0.f, 0.f, 0.f};

  char* Pw = Psm + wave * PSM_PER_WAVE;

  for (int kt = 0; kt < S_LEN / KVBLK; ++kt) {
    const int kv0 = kt * KVBLK;
    int mk[4][4];
#pragma unroll
    for (int r = 0; r < 4; ++r) {
      const int* mr = Mg + (size_t)(qrow0 + lg * 4 + r) * S_LEN + kv0 + lm;
#pragma unroll
      for (int st = 0; st < 4; ++st) mk[r][st] = mr[st * 16];
    }
    __syncthreads();
#pragma unroll
    for (int it = 0; it < 4; ++it) {
      int row = it * 16 + (tid >> 5);
      int col = (tid & 31) * 4;
      float4 v = *(const float4*)(Kb + (size_t)(kv0 + row) * HD + col);
      ushort4 hi, lo;
      hi.x = f2b(v.x); lo.x = f2b(v.x - b2f(hi.x));
      hi.y = f2b(v.y); lo.y = f2b(v.y - b2f(hi.y));
      hi.z = f2b(v.z); lo.z = f2b(v.z - b2f(hi.z));
      hi.w = f2b(v.w); lo.w = f2b(v.w - b2f(hi.w));
      int byo = (row * 256 + col * 2) ^ ((row & 7) << 4);
      *(ushort4*)(KsmH + byo) = hi;
      *(ushort4*)(KsmL + byo) = lo;
    }
    {
      int d = tid & 127;
      int kvh = (tid >> 7) * 16;
      const float* vc = Vb + (size_t)kv0 * HD + d;
#pragma unroll
      for (int j = 0; j < 4; ++j) {
        int kvb = kvh + j * 4;
        ushort4 h = make_ushort4(f2b(vc[(size_t)(kvb + 0) * HD]),
                                 f2b(vc[(size_t)(kvb + 1) * HD]),
                                 f2b(vc[(size_t)(kvb + 2) * HD]),
                                 f2b(vc[(size_t)(kvb + 3) * HD]));
        *(ushort4*)(Vsm + d * 144 + kvb * 2) = h;
      }
    }
    __syncthreads();

    f32x4 sf[4];
#pragma unroll
    for (int st = 0; st < 4; ++st) {
      f32x4 c = (f32x4){0.f, 0.f, 0.f, 0.f};
#pragma unroll
      for (int ch = 0; ch < 4; ++ch) {
        int krow = st * 16 + lm;
        int byo = (krow * 256 + (ch * 32 + lg * 8) * 2) ^ ((krow & 7) << 4);
        bf16x8 khi = *(const bf16x8*)(KsmH + byo);
        bf16x8 klo = *(const bf16x8*)(KsmL + byo);
        c = __builtin_amdgcn_mfma_f32_16x16x32_bf16(qhi[ch], khi, c, 0, 0, 0);
        c = __builtin_amdgcn_mfma_f32_16x16x32_bf16(qlo[ch], khi, c, 0, 0, 0);
        c = __builtin_amdgcn_mfma_f32_16x16x32_bf16(qhi[ch], klo, c, 0, 0, 0);
      }
      sf[st] = c;
    }

    float pv[4][4];
#pragma unroll
    for (int r = 0; r < 4; ++r) {
      float sc[4];
      float mx = -1e30f;
#pragma unroll
      for (int st = 0; st < 4; ++st) {
        float s = sf[st][r];
        sc[st] = mk[r][st] ? s : -1e-9f;
        mx = fmaxf(mx, sc[st]);
      }
      mx = fmaxf(mx, __shfl_xor(mx, 1));
      mx = fmaxf(mx, __shfl_xor(mx, 2));
      mx = fmaxf(mx, __shfl_xor(mx, 4));
      mx = fmaxf(mx, __shfl_xor(mx, 8));
      float mnew = fmaxf(mrun[r], mx);
      float scale = __expf(mrun[r] - mnew);
      float ps = 0.f;
#pragma unroll
      for (int st = 0; st < 4; ++st) {
        float p = __expf(sc[st] - mnew);
        pv[st][r] = p;
        ps += p;
      }
      ps += __shfl_xor(ps, 1);
      ps += __shfl_xor(ps, 2);
      ps += __shfl_xor(ps, 4);
      ps += __shfl_xor(ps, 8);
      lrun[r] = lrun[r] * scale + ps;
      mrun[r] = mnew;
#pragma unroll
      for (int dt = 0; dt < 8; ++dt) acc[dt][r] *= scale;
    }

#pragma unroll
    for (int st = 0; st < 4; ++st) {
#pragma unroll
      for (int r = 0; r < 4; ++r) {
        int row = lg * 4 + r;
        int col = st * 16 + lm;
        *(unsigned short*)(Pw + row * 144 + col * 2) = f2b(pv[st][r]);
      }
    }
    asm volatile("s_waitcnt lgkmcnt(0)" ::: "memory");
    __builtin_amdgcn_sched_barrier(0);

#pragma unroll
    for (int kk = 0; kk < 2; ++kk) {
      bf16x8 pa = *(const bf16x8*)(Pw + lm * 144 + kk * 64 + lg * 16);
#pragma unroll
      for (int dt = 0; dt < 8; ++dt) {
        bf16x8 vb = *(const bf16x8*)(Vsm + (dt * 16 + lm) * 144 + kk * 64 + lg * 16);
        acc[dt] = __builtin_amdgcn_mfma_f32_16x16x32_bf16(pa, vb, acc[dt], 0, 0, 0);
      }
    }
  }

  float invl[4];
#pragma unroll
  for (int r = 0; r < 4; ++r) invl[r] = 1.f / lrun[r];
  float* ob = Og + base;
#pragma unroll
  for (int dt = 0; dt < 8; ++dt) {
#pragma unroll
    for (int r = 0; r < 4; ++r) {
      ob[(size_t)(qrow0 + lg * 4 + r) * HD + dt * 16 + lm] = acc[dt][r] * invl[r];
    }
  }
}

extern "C" void kernel_launch(void* const* d_in, const int* in_sizes, int n_in,
                              void* d_out, int out_size, void* d_ws, size_t ws_size,
                              hipStream_t stream) {
  const float* key   = (const float*)d_in[0];
  const float* value = (const float*)d_in[1];
  const float* query = (const float*)d_in[2];
  const int*   mask  = (const int*)d_in[3];
  float* out = (float*)d_out;

  const size_t PLANE = (size_t)NBH * NKT * KIMG_TILE;  // 16MB
  if (ws_size >= 2 * PLANE) {
    char* kf = (char*)d_ws;
    char* vt = kf + PLANE;
    prep_kv<<<dim3(NBH * NKT), dim3(256), 0, stream>>>(key, value, kf, vt);
    attn_fwd5<<<dim3(NBH, S_LEN / QBLK), dim3(TPB), 0, stream>>>(kf, vt, query, mask, out);
  } else {
    attn_fwd<<<dim3(NBH, S_LEN / QBLK), dim3(TPB), 0, stream>>>(key, value, query, mask, out);
  }
}

// Round 11
// 305.604 us; speedup vs baseline: 1.1782x; 1.1782x over previous
//
#include <hip/hip_runtime.h>
#include <hip/hip_bf16.h>
#include <stdint.h>

#define S_LEN 2048
#define HD 128
#define QBLK 128          // fallback kernel geometry
#define KVBLK 64
#define TPB 512           // fallback
#define QBLK2 64          // fwd5 geometry
#define TPB2 256
#define NBH 32
#define NKT (S_LEN / KVBLK)      // 32 kv tiles
#define KIMG_TILE 16384          // 64x128 f16 LDS image bytes

typedef __attribute__((ext_vector_type(8))) _Float16 f16x8;
typedef __attribute__((ext_vector_type(8))) short s16x8;
typedef __attribute__((ext_vector_type(4))) float f32x4;

__device__ __forceinline__ short f2h(float f) {
  _Float16 h = (_Float16)f;
  return __builtin_bit_cast(short, h);
}
__device__ __forceinline__ unsigned short f2b(float f) {
  union { float fv; unsigned u; } v; v.fv = f;
  unsigned r = v.u + 0x7fffu + ((v.u >> 16) & 1u);
  return (unsigned short)(r >> 16);
}
__device__ __forceinline__ float b2f(unsigned short h) {
  union { unsigned u; float fv; } v; v.u = ((unsigned)h) << 16; return v.fv;
}
__device__ __forceinline__ unsigned pkrtz(float a, float b) {
  return __builtin_bit_cast(unsigned, __builtin_amdgcn_cvt_pkrtz(a, b));
}

typedef __attribute__((address_space(3))) uint32_t lds_u32_t;
typedef __attribute__((address_space(1))) const uint32_t glb_u32_t;
__device__ __forceinline__ void gll16(const void* g, void* l) {
  __builtin_amdgcn_global_load_lds((glb_u32_t*)g, (lds_u32_t*)l, 16, 0, 0);
}

// ============================================================================
// Pre-pass v2: LINEAR coalesced writes; swizzle moved to the read side.
// Output images byte-identical to previous rounds (same f2h of same values):
//   K:  out slot s of row r  <- input slot s ^ (r&7)   (16B slots, 256B rows)
//   Vt: out slot8 s of row d <- input kv-group s ^ (d&7) (16B slots, 128B rows)
// ============================================================================
__global__ __launch_bounds__(256) void prep_kv(
    const float* __restrict__ Kg, const float* __restrict__ Vg,
    char* __restrict__ KfI, char* __restrict__ VtI) {
  __shared__ __align__(16) char vlds[64 * 528];   // V tile f32, 528B row stride
  const int t = threadIdx.x;
  const int bh = blockIdx.x >> 5;
  const int kt = blockIdx.x & 31;
  const size_t base = ((size_t)bh * S_LEN + (size_t)kt * KVBLK) * HD;
  const size_t tbase = ((size_t)bh * NKT + kt) * KIMG_TILE;

  // ---- stage V tile f32 -> LDS, coalesced ----
#pragma unroll
  for (int it = 0; it < 8; ++it) {
    int idx = it * 256 + t;
    int kv = idx >> 5;
    int cb = (idx & 31) * 16;
    float4 v = *(const float4*)((const char*)(Vg + base) + (size_t)kv * 512 + cb);
    *(float4*)(vlds + kv * 528 + cb) = v;
  }

  // ---- K: register path, swizzled READS within row, linear writes ----
#pragma unroll
  for (int i = 0; i < 4; ++i) {
    int o = i * 4096 + t * 16;
    int row = o >> 8;
    int sin = ((o >> 4) & 15) ^ (row & 7);
    const float* src = Kg + base + (size_t)row * HD + sin * 8;
    float4 a = *(const float4*)src;
    float4 b = *(const float4*)(src + 4);
    s16x8 h;
    h[0] = f2h(a.x); h[1] = f2h(a.y); h[2] = f2h(a.z); h[3] = f2h(a.w);
    h[4] = f2h(b.x); h[5] = f2h(b.y); h[6] = f2h(b.z); h[7] = f2h(b.w);
    *(s16x8*)(KfI + tbase + o) = h;
  }

  __syncthreads();

  // ---- Vt: LDS gather at inverse-swizzled (d,kv), linear writes ----
#pragma unroll
  for (int i = 0; i < 4; ++i) {
    int o = i * 4096 + t * 16;
    int d = o >> 7;
    int kvb = (((o >> 4) & 7) ^ (d & 7)) * 8;
    s16x8 hv;
#pragma unroll
    for (int j = 0; j < 8; ++j)
      hv[j] = f2h(*(const float*)(vlds + (kvb + j) * 528 + d * 4));
    *(s16x8*)(VtI + tbase + o) = hv;
  }
}

// ============================================================================
// Swapped-operand attention, small-block TLP version:
// 256 threads (4 waves), QBLK2=64, grid 1024 blocks -> 4-5 blocks/CU.
// LDS: Kf 16K | Vt 16K = 32KB single buffer. Per-wave body identical to R10.
// ============================================================================
#define SMEMF5 32768

__global__ __launch_bounds__(TPB2, 4) void attn_fwd5(
    const char* __restrict__ KfI, const char* __restrict__ VtI,
    const float* __restrict__ Qg, const int* __restrict__ Mg,
    float* __restrict__ Og) {
  __shared__ __align__(16) char smem[SMEMF5];

  const int tid = threadIdx.x;
  const int wave = tid >> 6;       // 0..3
  const int lane = tid & 63;
  const int lm = lane & 15;
  const int lg = lane >> 4;

  const int bh = blockIdx.x;
  const int q0 = blockIdx.y * QBLK2;
  const int qrow0 = q0 + wave * 16;
  const size_t base = (size_t)bh * S_LEN * HD;
  const float* Qb = Qg + base;

  // ---- Q fragments: f16, 1/T = 1.25 folded. row=qrow0+lm, k=lg*8+e ----
  f16x8 qf[4];
#pragma unroll
  for (int c = 0; c < 4; ++c) {
    const float* src = Qb + (size_t)(qrow0 + lm) * HD + c * 32 + lg * 8;
    float4 a = *(const float4*)src;
    float4 b = *(const float4*)(src + 4);
    float qs[8] = {a.x, a.y, a.z, a.w, b.x, b.y, b.z, b.w};
    f16x8 f;
#pragma unroll
    for (int j = 0; j < 8; ++j) f[j] = (_Float16)(qs[j] * 1.25f);
    qf[c] = f;
  }

  // acc[dt][r] = O[qrow0+lm][dt*16 + 4*lg + r]
  f32x4 acc[8];
#pragma unroll
  for (int i = 0; i < 8; ++i) acc[i] = (f32x4){0.f, 0.f, 0.f, 0.f};
  float mrun = -1e30f;
  float lrun = 0.f;

  const int* Mrow = Mg + (size_t)(qrow0 + lm) * S_LEN + 4 * lg;

  for (int kt = 0; kt < NKT; ++kt) {
    const int kv0 = kt * KVBLK;

    __syncthreads();  // all waves done reading buffer (previous tile)

    // ---- stage K,Vt tile via async global->LDS: 8 issues/lane ----
    {
      const size_t tb = ((size_t)bh * NKT + kt) * KIMG_TILE;
      const int lo = lane * 16;
#pragma unroll
      for (int i = 0; i < 4; ++i) {
        int off = i * 4096 + wave * 1024;
        gll16(KfI + tb + off + lo, smem + off);
        gll16(VtI + tb + off + lo, smem + 16384 + off);
      }
    }
    // ---- mask: int4 per subtile, kv = kv0 + st*16 + 4*lg + r ----
    int4 mk4[4];
#pragma unroll
    for (int st = 0; st < 4; ++st)
      mk4[st] = *(const int4*)(Mrow + kv0 + st * 16);

    __syncthreads();  // stage + mask drained

    // ---- QK^T swapped: lane gets row q=lm, kv=st*16+4lg+r ----
    __builtin_amdgcn_s_setprio(1);
    f32x4 sf[4];
#pragma unroll
    for (int st = 0; st < 4; ++st) {
      f32x4 c = (f32x4){0.f, 0.f, 0.f, 0.f};
#pragma unroll
      for (int ch = 0; ch < 4; ++ch) {
        int krow = st * 16 + lm;
        int byo = (krow * 256 + ch * 64 + lg * 16) ^ ((krow & 7) << 4);
        f16x8 kf = *(const f16x8*)(smem + byo);
        c = __builtin_amdgcn_mfma_f32_16x16x32_f16(kf, qf[ch], c, 0, 0, 0);
      }
      sf[st] = c;
    }
    __builtin_amdgcn_s_setprio(0);

    // ---- mask + in-register online softmax ----
    float p[4][4];
    float mx = -1e30f;
#pragma unroll
    for (int st = 0; st < 4; ++st) {
      int mr[4] = {mk4[st].x, mk4[st].y, mk4[st].z, mk4[st].w};
#pragma unroll
      for (int r = 0; r < 4; ++r) {
        float s = mr[r] ? sf[st][r] : -1e-9f;
        p[st][r] = s;
        mx = fmaxf(mx, s);
      }
    }
    mx = fmaxf(mx, __shfl_xor(mx, 16));
    mx = fmaxf(mx, __shfl_xor(mx, 32));

    bool need = mx > mrun + 8.f;       // defer-rescale (T13)
    if (__any(need)) {
      float mnew = fmaxf(mrun, mx);
      float scale = __expf(mrun - mnew);
      lrun *= scale;
      mrun = mnew;
#pragma unroll
      for (int dt = 0; dt < 8; ++dt) acc[dt] *= scale;
    }
    float ps = 0.f;
#pragma unroll
    for (int st = 0; st < 4; ++st)
#pragma unroll
      for (int r = 0; r < 4; ++r) {
        float e = __expf(p[st][r] - mrun);
        p[st][r] = e;
        ps += e;
      }
    ps += __shfl_xor(ps, 16);
    ps += __shfl_xor(ps, 32);
    lrun += ps;

    // ---- pack P to f16 pairs ----
    unsigned w[4][2];
#pragma unroll
    for (int st = 0; st < 4; ++st)
#pragma unroll
      for (int rp = 0; rp < 2; ++rp)
        w[st][rp] = pkrtz(p[st][2 * rp], p[st][2 * rp + 1]);

    // ---- PV swapped: O^T += V^T * P^T, B-frag via lane redistribution ----
#pragma unroll
    for (int kk = 0; kk < 2; ++kk) {
      int words[4];
#pragma unroll
      for (int i = 0; i < 4; ++i) {
        int src = lm + 16 * ((lg & 1) * 2 + (i >> 1));
        int wa = __shfl((int)w[2 * kk + 0][i & 1], src);
        int wb = __shfl((int)w[2 * kk + 1][i & 1], src);
        words[i] = (lg >> 1) ? wb : wa;
      }
      union { int v[4]; f16x8 h; } pb;
      pb.v[0] = words[0]; pb.v[1] = words[1];
      pb.v[2] = words[2]; pb.v[3] = words[3];

      __builtin_amdgcn_s_setprio(1);
#pragma unroll
      for (int dt = 0; dt < 8; ++dt) {
        int vrow = dt * 16 + lm;
        int byo = (vrow * 128 + (kk * 32 + lg * 8) * 2) ^ ((vrow & 7) << 4);
        f16x8 va = *(const f16x8*)(smem + 16384 + byo);
        acc[dt] = __builtin_amdgcn_mfma_f32_16x16x32_f16(va, pb.h, acc[dt], 0, 0, 0);
      }
      __builtin_amdgcn_s_setprio(0);
    }
  }

  // ---- epilogue: O[qrow0+lm][dt*16+4lg .. +3] = acc[dt] / lrun ----
  float invl = 1.f / lrun;
  float* ob = Og + base + (size_t)(qrow0 + lm) * HD;
#pragma unroll
  for (int dt = 0; dt < 8; ++dt) {
    float4 o;
    o.x = acc[dt][0] * invl;
    o.y = acc[dt][1] * invl;
    o.z = acc[dt][2] * invl;
    o.w = acc[dt][3] * invl;
    *(float4*)(ob + dt * 16 + 4 * lg) = o;
  }
}

// ============================================================================
// Fallback (Round-3 verified bf16 hi/lo kernel) if ws too small for images.
// ============================================================================
typedef __attribute__((ext_vector_type(8))) short bf16x8;
#define KSM_BYTES (KVBLK * HD * 2)
#define VSM_BYTES (HD * 72 * 2)
#define PSM_PER_WAVE (16 * 72 * 2)
#define SMEM_BYTES (2 * KSM_BYTES + VSM_BYTES + 8 * PSM_PER_WAVE)

__global__ __launch_bounds__(TPB, 2) void attn_fwd(
    const float* __restrict__ Kg, const float* __restrict__ Vg,
    const float* __restrict__ Qg, const int* __restrict__ Mg,
    float* __restrict__ Og) {
  __shared__ __align__(16) char smem[SMEM_BYTES];
  char* KsmH = smem;
  char* KsmL = smem + KSM_BYTES;
  char* Vsm = smem + 2 * KSM_BYTES;
  char* Psm = smem + 2 * KSM_BYTES + VSM_BYTES;

  const int tid = threadIdx.x;
  const int wave = tid >> 6;
  const int lane = tid & 63;
  const int lm = lane & 15;
  const int lg = lane >> 4;

  const int bh = blockIdx.x;
  const int q0 = blockIdx.y * QBLK;
  const int qrow0 = q0 + wave * 16;

  const size_t base = (size_t)bh * S_LEN * HD;
  const float* Kb = Kg + base;
  const float* Vb = Vg + base;
  const float* Qb = Qg + base;

  bf16x8 qhi[4], qlo[4];
#pragma unroll
  for (int c = 0; c < 4; ++c) {
    const float* src = Qb + (size_t)(qrow0 + lm) * HD + c * 32 + lg * 8;
    float4 a = *(const float4*)src;
    float4 b = *(const float4*)(src + 4);
    float qs[8] = {a.x, a.y, a.z, a.w, b.x, b.y, b.z, b.w};
    bf16x8 fh, fl;
#pragma unroll
    for (int j = 0; j < 8; ++j) {
      float v = qs[j] * 1.25f;
      unsigned short h = f2b(v);
      fh[j] = (short)h;
      fl[j] = (short)f2b(v - b2f(h));
    }
    qhi[c] = fh;
    qlo[c] = fl;
  }

  f32x4 acc[8];
#pragma unroll
  for (int i = 0; i < 8; ++i) acc[i] = (f32x4){0.f, 0.f, 0.f, 0.f};
  float mrun[4] = {-1e30f, -1e30f, -1e30f, -1e30f};
  float lrun[4] = {0.f, 0.f, 0.f, 0.f};

  char* Pw = Psm + wave * PSM_PER_WAVE;

  for (int kt = 0; kt < S_LEN / KVBLK; ++kt) {
    const int kv0 = kt * KVBLK;
    int mk[4][4];
#pragma unroll
    for (int r = 0; r < 4; ++r) {
      const int* mr = Mg + (size_t)(qrow0 + lg * 4 + r) * S_LEN + kv0 + lm;
#pragma unroll
      for (int st = 0; st < 4; ++st) mk[r][st] = mr[st * 16];
    }
    __syncthreads();
#pragma unroll
    for (int it = 0; it < 4; ++it) {
      int row = it * 16 + (tid >> 5);
      int col = (tid & 31) * 4;
      float4 v = *(const float4*)(Kb + (size_t)(kv0 + row) * HD + col);
      ushort4 hi, lo;
      hi.x = f2b(v.x); lo.x = f2b(v.x - b2f(hi.x));
      hi.y = f2b(v.y); lo.y = f2b(v.y - b2f(hi.y));
      hi.z = f2b(v.z); lo.z = f2b(v.z - b2f(hi.z));
      hi.w = f2b(v.w); lo.w = f2b(v.w - b2f(hi.w));
      int byo = (row * 256 + col * 2) ^ ((row & 7) << 4);
      *(ushort4*)(KsmH + byo) = hi;
      *(ushort4*)(KsmL + byo) = lo;
    }
    {
      int d = tid & 127;
      int kvh = (tid >> 7) * 16;
      const float* vc = Vb + (size_t)kv0 * HD + d;
#pragma unroll
      for (int j = 0; j < 4; ++j) {
        int kvb = kvh + j * 4;
        ushort4 h = make_ushort4(f2b(vc[(size_t)(kvb + 0) * HD]),
                                 f2b(vc[(size_t)(kvb + 1) * HD]),
                                 f2b(vc[(size_t)(kvb + 2) * HD]),
                                 f2b(vc[(size_t)(kvb + 3) * HD]));
        *(ushort4*)(Vsm + d * 144 + kvb * 2) = h;
      }
    }
    __syncthreads();

    f32x4 sf[4];
#pragma unroll
    for (int st = 0; st < 4; ++st) {
      f32x4 c = (f32x4){0.f, 0.f, 0.f, 0.f};
#pragma unroll
      for (int ch = 0; ch < 4; ++ch) {
        int krow = st * 16 + lm;
        int byo = (krow * 256 + (ch * 32 + lg * 8) * 2) ^ ((krow & 7) << 4);
        bf16x8 khi = *(const bf16x8*)(KsmH + byo);
        bf16x8 klo = *(const bf16x8*)(KsmL + byo);
        c = __builtin_amdgcn_mfma_f32_16x16x32_bf16(qhi[ch], khi, c, 0, 0, 0);
        c = __builtin_amdgcn_mfma_f32_16x16x32_bf16(qlo[ch], khi, c, 0, 0, 0);
        c = __builtin_amdgcn_mfma_f32_16x16x32_bf16(qhi[ch], klo, c, 0, 0, 0);
      }
      sf[st] = c;
    }

    float pv[4][4];
#pragma unroll
    for (int r = 0; r < 4; ++r) {
      float sc[4];
      float mx = -1e30f;
#pragma unroll
      for (int st = 0; st < 4; ++st) {
        float s = sf[st][r];
        sc[st] = mk[r][st] ? s : -1e-9f;
        mx = fmaxf(mx, sc[st]);
      }
      mx = fmaxf(mx, __shfl_xor(mx, 1));
      mx = fmaxf(mx, __shfl_xor(mx, 2));
      mx = fmaxf(mx, __shfl_xor(mx, 4));
      mx = fmaxf(mx, __shfl_xor(mx, 8));
      float mnew = fmaxf(mrun[r], mx);
      float scale = __expf(mrun[r] - mnew);
      float ps = 0.f;
#pragma unroll
      for (int st = 0; st < 4; ++st) {
        float p = __expf(sc[st] - mnew);
        pv[st][r] = p;
        ps += p;
      }
      ps += __shfl_xor(ps, 1);
      ps += __shfl_xor(ps, 2);
      ps += __shfl_xor(ps, 4);
      ps += __shfl_xor(ps, 8);
      lrun[r] = lrun[r] * scale + ps;
      mrun[r] = mnew;
#pragma unroll
      for (int dt = 0; dt < 8; ++dt) acc[dt][r] *= scale;
    }

#pragma unroll
    for (int st = 0; st < 4; ++st) {
#pragma unroll
      for (int r = 0; r < 4; ++r) {
        int row = lg * 4 + r;
        int col = st * 16 + lm;
        *(unsigned short*)(Pw + row * 144 + col * 2) = f2b(pv[st][r]);
      }
    }
    asm volatile("s_waitcnt lgkmcnt(0)" ::: "memory");
    __builtin_amdgcn_sched_barrier(0);

#pragma unroll
    for (int kk = 0; kk < 2; ++kk) {
      bf16x8 pa = *(const bf16x8*)(Pw + lm * 144 + kk * 64 + lg * 16);
#pragma unroll
      for (int dt = 0; dt < 8; ++dt) {
        bf16x8 vb = *(const bf16x8*)(Vsm + (dt * 16 + lm) * 144 + kk * 64 + lg * 16);
        acc[dt] = __builtin_amdgcn_mfma_f32_16x16x32_bf16(pa, vb, acc[dt], 0, 0, 0);
      }
    }
  }

  float invl[4];
#pragma unroll
  for (int r = 0; r < 4; ++r) invl[r] = 1.f / lrun[r];
  float* ob = Og + base;
#pragma unroll
  for (int dt = 0; dt < 8; ++dt) {
#pragma unroll
    for (int r = 0; r < 4; ++r) {
      ob[(size_t)(qrow0 + lg * 4 + r) * HD + dt * 16 + lm] = acc[dt][r] * invl[r];
    }
  }
}

extern "C" void kernel_launch(void* const* d_in, const int* in_sizes, int n_in,
                              void* d_out, int out_size, void* d_ws, size_t ws_size,
                              hipStream_t stream) {
  const float* key   = (const float*)d_in[0];
  const float* value = (const float*)d_in[1];
  const float* query = (const float*)d_in[2];
  const int*   mask  = (const int*)d_in[3];
  float* out = (float*)d_out;

  const size_t PLANE = (size_t)NBH * NKT * KIMG_TILE;  // 16MB
  if (ws_size >= 2 * PLANE) {
    char* kf = (char*)d_ws;
    char* vt = kf + PLANE;
    prep_kv<<<dim3(NBH * NKT), dim3(256), 0, stream>>>(key, value, kf, vt);
    attn_fwd5<<<dim3(NBH, S_LEN / QBLK2), dim3(TPB2), 0, stream>>>(kf, vt, query, mask, out);
  } else {
    attn_fwd<<<dim3(NBH, S_LEN / QBLK), dim3(TPB), 0, stream>>>(key, value, query, mask, out);
  }
}